// Round 4
// baseline (440.735 us; speedup 1.0000x reference)
//
#include <hip/hip_runtime.h>

#define NBQ 12544
#define DM  256
#define MM  2048

typedef __attribute__((ext_vector_type(8))) __bf16 bf16x8;
typedef __attribute__((ext_vector_type(4))) float  floatx4;

__device__ __forceinline__ ushort f2bf(float x) {
    unsigned u = __float_as_uint(x);
    u += 0x7fffu + ((u >> 16) & 1u);   // RNE
    return (ushort)(u >> 16);
}
__device__ __forceinline__ float bf2f(ushort h) {
    return __uint_as_float(((unsigned)h) << 16);
}

// ---------------- MFMA projection: C = A(fp32) * W(fp32)^T, bf16 out ----------------
// TRANS=0: C[r][c] row-major [nrows x 256]; TRANS=1: C[c][r] = [256 x nrows]
template <int TRANS>
__global__ __launch_bounds__(256) void gemm_proj_mfma(
    const float* __restrict__ A, const float* __restrict__ W,
    ushort* __restrict__ C, int nrows)
{
    __shared__ ushort As[64][72];   // [row][k], stride 144B -> 2-way banks
    __shared__ ushort Ws[64][72];   // [col][k]; reused as transpose buffer for TRANS=1
    const int tid  = threadIdx.x;
    const int wv   = tid >> 6;
    const int lane = tid & 63;
    const int quad = lane >> 4;
    const int l16  = lane & 15;
    const int r0 = blockIdx.x * 64;
    const int c0 = blockIdx.y * 64;
    const int rw = (wv & 1) * 32;
    const int cw = (wv >> 1) * 32;

    floatx4 acc[2][2];
    #pragma unroll
    for (int i = 0; i < 2; ++i)
        #pragma unroll
        for (int j = 0; j < 2; ++j)
            acc[i][j] = (floatx4){0.f, 0.f, 0.f, 0.f};

    for (int d0 = 0; d0 < 256; d0 += 64) {
        __syncthreads();
        #pragma unroll
        for (int it = 0; it < 4; ++it) {
            int idx = tid + it * 256;          // 1024 float4-chunks: 64 rows x 16
            int r = idx >> 4, c4 = (idx & 15) * 4;
            float4 a4 = *(const float4*)(A + (size_t)(r0 + r) * 256 + d0 + c4);
            float4 w4 = *(const float4*)(W + (size_t)(c0 + r) * 256 + d0 + c4);
            ushort4 ab, wb;
            ab.x = f2bf(a4.x); ab.y = f2bf(a4.y); ab.z = f2bf(a4.z); ab.w = f2bf(a4.w);
            wb.x = f2bf(w4.x); wb.y = f2bf(w4.y); wb.z = f2bf(w4.z); wb.w = f2bf(w4.w);
            *(ushort4*)&As[r][c4] = ab;
            *(ushort4*)&Ws[r][c4] = wb;
        }
        __syncthreads();
        #pragma unroll
        for (int kk = 0; kk < 64; kk += 32) {
            bf16x8 aA0 = *(const bf16x8*)&As[rw + l16][kk + quad * 8];
            bf16x8 aA1 = *(const bf16x8*)&As[rw + 16 + l16][kk + quad * 8];
            bf16x8 bW0 = *(const bf16x8*)&Ws[cw + l16][kk + quad * 8];
            bf16x8 bW1 = *(const bf16x8*)&Ws[cw + 16 + l16][kk + quad * 8];
            acc[0][0] = __builtin_amdgcn_mfma_f32_16x16x32_bf16(aA0, bW0, acc[0][0], 0, 0, 0);
            acc[0][1] = __builtin_amdgcn_mfma_f32_16x16x32_bf16(aA0, bW1, acc[0][1], 0, 0, 0);
            acc[1][0] = __builtin_amdgcn_mfma_f32_16x16x32_bf16(aA1, bW0, acc[1][0], 0, 0, 0);
            acc[1][1] = __builtin_amdgcn_mfma_f32_16x16x32_bf16(aA1, bW1, acc[1][1], 0, 0, 0);
        }
    }

    if (!TRANS) {
        #pragma unroll
        for (int ag = 0; ag < 2; ++ag)
            #pragma unroll
            for (int cg = 0; cg < 2; ++cg)
                #pragma unroll
                for (int i = 0; i < 4; ++i)
                    C[(size_t)(r0 + rw + ag * 16 + quad * 4 + i) * 256
                      + c0 + cw + cg * 16 + l16] = f2bf(acc[ag][cg][i]);
    } else {
        __syncthreads();  // done with Ws tiles
        #pragma unroll
        for (int ag = 0; ag < 2; ++ag)
            #pragma unroll
            for (int cg = 0; cg < 2; ++cg)
                #pragma unroll
                for (int i = 0; i < 4; ++i)
                    Ws[cw + cg * 16 + l16][rw + ag * 16 + quad * 4 + i] = f2bf(acc[ag][cg][i]);
        __syncthreads();
        const int col = tid >> 2;
        const int seg = (tid & 3) * 16;
        #pragma unroll
        for (int j = 0; j < 2; ++j)
            *(uint4*)(C + (size_t)(c0 + col) * nrows + r0 + seg + j * 8) =
                *(const uint4*)&Ws[col][seg + j * 8];
    }
}

// ---------------- row stats from bf16 rows (mean, unbiased var) ----------------
__global__ __launch_bounds__(256) void row_stats_bf16(
    const ushort* __restrict__ X, float* __restrict__ mean, float* __restrict__ var)
{
    const int row  = blockIdx.x * 4 + (threadIdx.x >> 6);
    const int lane = threadIdx.x & 63;
    ushort4 u = *(const ushort4*)(X + (size_t)row * 256 + lane * 4);
    float a = bf2f(u.x), b = bf2f(u.y), c = bf2f(u.z), d = bf2f(u.w);
    float s  = a + b + c + d;
    float ss = a * a + b * b + c * c + d * d;
    #pragma unroll
    for (int off = 32; off > 0; off >>= 1) {
        s  += __shfl_down(s, off);
        ss += __shfl_down(ss, off);
    }
    if (lane == 0) {
        float m = s * (1.f / 256.f);
        mean[row] = m;
        var[row]  = (ss - 256.f * m * m) * (1.f / 255.f);
    }
}

// ---------------- fused dual attention, MFMA, 64-key tiles ----------------
// Block: 32 queries, 4 waves. Scores: wave (qsel=w&1, ksel=w>>1) -> 16q x 32k.
// PV: wave owns d-quarter (64 dims), both q-halves; V/VF read direct from global (L2).
__global__ __launch_bounds__(256, 2) void fused_attn_mfma(
    const ushort* __restrict__ Qb,  const ushort* __restrict__ QFb,
    const ushort* __restrict__ Kb,  const ushort* __restrict__ KFb,
    const ushort* __restrict__ Vtb, const ushort* __restrict__ VFtb,
    const float* __restrict__ qm_, const float* __restrict__ qv_,
    const float* __restrict__ km_, const float* __restrict__ kv_,
    float* __restrict__ out)
{
    __shared__ ushort K_lds[64][264];    // stride 528B -> 2-way banks
    __shared__ ushort KF_lds[64][264];
    __shared__ ushort P_lds[2][32][72];  // [branch][q][key], stride 144B -> 2-way
    // total LDS = 2*33792 + 9216 = 76800 B -> 2 blocks/CU

    const int tid  = threadIdx.x;
    const int wv   = tid >> 6;
    const int lane = tid & 63;
    const int quad = lane >> 4;
    const int l16  = lane & 15;
    const int qsel = wv & 1;
    const int ksel = wv >> 1;
    const int q0   = blockIdx.x * 32;
    const int dbase = wv * 64;           // PV dim quarter

    // Q A-fragments in registers for the whole key loop
    bf16x8 aQ[8], aQF[8];
    {
        const ushort* qp  = Qb  + (size_t)(q0 + qsel * 16 + l16) * DM + quad * 8;
        const ushort* qfp = QFb + (size_t)(q0 + qsel * 16 + l16) * DM + quad * 8;
        #pragma unroll
        for (int s = 0; s < 8; ++s) {
            aQ[s]  = *(const bf16x8*)(qp  + s * 32);
            aQF[s] = *(const bf16x8*)(qfp + s * 32);
        }
    }
    float qmv[4], qvv[4];
    #pragma unroll
    for (int r = 0; r < 4; ++r) {
        int qg = q0 + qsel * 16 + quad * 4 + r;
        qmv[r] = qm_[qg]; qvv[r] = qv_[qg];
    }

    floatx4 acc_c[2][4], acc_s[2][4];    // [qhalf][dgroup]
    #pragma unroll
    for (int qh = 0; qh < 2; ++qh)
        #pragma unroll
        for (int dg = 0; dg < 4; ++dg) {
            acc_c[qh][dg] = (floatx4){0.f, 0.f, 0.f, 0.f};
            acc_s[qh][dg] = (floatx4){0.f, 0.f, 0.f, 0.f};
        }
    float denc_r[4] = {0.f, 0.f, 0.f, 0.f};
    float dens_r[4] = {0.f, 0.f, 0.f, 0.f};

    for (int kt = 0; kt < MM; kt += 64) {
        __syncthreads();  // previous tile's LDS fully consumed
        // stage K/KF (64 x 256 bf16 each): 2048 uint4-chunks = 64 rows x 32 chunks
        #pragma unroll
        for (int it = 0; it < 8; ++it) {
            int idx = tid + it * 256;
            int r = idx >> 5, c8 = (idx & 31) * 8;
            *(uint4*)&K_lds[r][c8]  = *(const uint4*)(Kb  + (size_t)(kt + r) * DM + c8);
            *(uint4*)&KF_lds[r][c8] = *(const uint4*)(KFb + (size_t)(kt + r) * DM + c8);
        }
        __syncthreads();

        // prefetch first-half (kc=0) V fragments for this wave's d-quarter
        bf16x8 vc0[4], vs0[4];
        #pragma unroll
        for (int dg = 0; dg < 4; ++dg) {
            const size_t vrow = (size_t)(dbase + dg * 16 + l16) * MM + kt + quad * 8;
            vc0[dg] = *(const bf16x8*)(Vtb  + vrow);
            vs0[dg] = *(const bf16x8*)(VFtb + vrow);
        }

        // ---- scores: 16q x 32k per wave (2 kgroups), both branches ----
        floatx4 sc[2], sd[2];
        #pragma unroll
        for (int kg = 0; kg < 2; ++kg) {
            sc[kg] = (floatx4){0.f, 0.f, 0.f, 0.f};
            sd[kg] = (floatx4){0.f, 0.f, 0.f, 0.f};
        }
        #pragma unroll
        for (int s = 0; s < 8; ++s) {
            #pragma unroll
            for (int kg = 0; kg < 2; ++kg) {
                bf16x8 bK  = *(const bf16x8*)&K_lds[ksel * 32 + kg * 16 + l16][s * 32 + quad * 8];
                bf16x8 bKF = *(const bf16x8*)&KF_lds[ksel * 32 + kg * 16 + l16][s * 32 + quad * 8];
                sc[kg] = __builtin_amdgcn_mfma_f32_16x16x32_bf16(aQ[s],  bK,  sc[kg], 0, 0, 0);
                sd[kg] = __builtin_amdgcn_mfma_f32_16x16x32_bf16(aQF[s], bKF, sd[kg], 0, 0, 0);
            }
        }

        // ---- epilogue: exp(score/16), SSIM -> P (bf16), denominator partials ----
        #pragma unroll
        for (int kg = 0; kg < 2; ++kg) {
            int kcol = kt + ksel * 32 + kg * 16 + l16;
            float kmv = km_[kcol], kvv = kv_[kcol];
            #pragma unroll
            for (int r = 0; r < 4; ++r) {
                float p1  = __expf(sc[kg][r] * 0.0625f);
                float mp  = qmv[r] * kmv;
                float cov = (sd[kg][r] - 256.f * mp) * (1.f / 255.f);
                float num = (2.f * mp + 0.01f) * (2.f * cov + 0.03f);
                float den = (qmv[r] * qmv[r] + kmv * kmv + 0.01f) * (qvv[r] + kvv + 0.03f);
                float p2  = __expf(num / (den + 1e-8f));
                P_lds[0][qsel * 16 + quad * 4 + r][ksel * 32 + kg * 16 + l16] = f2bf(p1);
                P_lds[1][qsel * 16 + quad * 4 + r][ksel * 32 + kg * 16 + l16] = f2bf(p2);
                denc_r[r] += p1;
                dens_r[r] += p2;
            }
        }
        __syncthreads();

        // ---- PV: A = P (both q-halves), B = V/VF direct global, d-quarter ----
        #pragma unroll
        for (int kc2 = 0; kc2 < 2; ++kc2) {
            const int kc = kc2 * 32;
            bf16x8 aPc0 = *(const bf16x8*)&P_lds[0][l16][kc + quad * 8];
            bf16x8 aPc1 = *(const bf16x8*)&P_lds[0][16 + l16][kc + quad * 8];
            bf16x8 aPs0 = *(const bf16x8*)&P_lds[1][l16][kc + quad * 8];
            bf16x8 aPs1 = *(const bf16x8*)&P_lds[1][16 + l16][kc + quad * 8];
            #pragma unroll
            for (int dg = 0; dg < 4; ++dg) {
                bf16x8 bV, bVF;
                if (kc2 == 0) { bV = vc0[dg]; bVF = vs0[dg]; }
                else {
                    const size_t vrow = (size_t)(dbase + dg * 16 + l16) * MM + kt + 32 + quad * 8;
                    bV  = *(const bf16x8*)(Vtb  + vrow);
                    bVF = *(const bf16x8*)(VFtb + vrow);
                }
                acc_c[0][dg] = __builtin_amdgcn_mfma_f32_16x16x32_bf16(aPc0, bV,  acc_c[0][dg], 0, 0, 0);
                acc_c[1][dg] = __builtin_amdgcn_mfma_f32_16x16x32_bf16(aPc1, bV,  acc_c[1][dg], 0, 0, 0);
                acc_s[0][dg] = __builtin_amdgcn_mfma_f32_16x16x32_bf16(aPs0, bVF, acc_s[0][dg], 0, 0, 0);
                acc_s[1][dg] = __builtin_amdgcn_mfma_f32_16x16x32_bf16(aPs1, bVF, acc_s[1][dg], 0, 0, 0);
            }
        }
    }

    // ---- denominators: reduce over 16 key-lanes, combine k-halves via LDS ----
    #pragma unroll
    for (int r = 0; r < 4; ++r) {
        #pragma unroll
        for (int m = 1; m < 16; m <<= 1) {
            denc_r[r] += __shfl_xor(denc_r[r], m, 64);
            dens_r[r] += __shfl_xor(dens_r[r], m, 64);
        }
    }
    __syncthreads();  // all PV reads of P done; safe to alias
    float* denbuf = (float*)P_lds;  // [2 branch][2 ksel][32 q]
    if (l16 == 0) {
        #pragma unroll
        for (int r = 0; r < 4; ++r) {
            int q32 = qsel * 16 + quad * 4 + r;
            denbuf[ksel * 32 + q32]      = denc_r[r];
            denbuf[64 + ksel * 32 + q32] = dens_r[r];
        }
    }
    __syncthreads();

    // ---- output: wave's d-quarter, both q-halves (64B-coalesced stores) ----
    #pragma unroll
    for (int qh = 0; qh < 2; ++qh) {
        #pragma unroll
        for (int r = 0; r < 4; ++r) {
            int q32 = qh * 16 + quad * 4 + r;
            float rc = 1.f / (denbuf[q32] + denbuf[32 + q32]);
            float rs = 1.f / (denbuf[64 + q32] + denbuf[96 + q32]);
            #pragma unroll
            for (int dg = 0; dg < 4; ++dg)
                out[(size_t)(q0 + q32) * DM + dbase + dg * 16 + l16] =
                    acc_c[qh][dg][r] * rc + acc_s[qh][dg][r] * rs;
        }
    }
}

extern "C" void kernel_launch(void* const* d_in, const int* in_sizes, int n_in,
                              void* d_out, int out_size, void* d_ws, size_t ws_size,
                              hipStream_t stream)
{
    const float* x      = (const float*)d_in[0];
    const float* ch_mem = (const float*)d_in[1];
    const float* ch_wq  = (const float*)d_in[2];
    const float* ch_wk  = (const float*)d_in[3];
    const float* ch_wv  = (const float*)d_in[4];
    const float* sp_mem = (const float*)d_in[5];
    const float* sp_wq  = (const float*)d_in[6];
    const float* sp_wk  = (const float*)d_in[7];
    const float* sp_wv  = (const float*)d_in[8];
    float* out = (float*)d_out;

    ushort* Qb   = (ushort*)d_ws;                 // [12544][256]
    ushort* QFb  = Qb   + (size_t)NBQ * DM;
    ushort* Kb   = QFb  + (size_t)NBQ * DM;       // [2048][256]
    ushort* KFb  = Kb   + (size_t)MM * DM;
    ushort* Vtb  = KFb  + (size_t)MM * DM;        // [256][2048] transposed
    ushort* VFtb = Vtb  + (size_t)MM * DM;
    float*  qm   = (float*)(VFtb + (size_t)MM * DM);
    float*  qv   = qm + NBQ;
    float*  km   = qv + NBQ;
    float*  kv   = km + MM;

    dim3 blk(256);
    gemm_proj_mfma<0><<<dim3(196, 4), blk, 0, stream>>>(x,      ch_wq, Qb,   NBQ);
    gemm_proj_mfma<0><<<dim3(196, 4), blk, 0, stream>>>(x,      sp_wq, QFb,  NBQ);
    gemm_proj_mfma<0><<<dim3(32, 4),  blk, 0, stream>>>(ch_mem, ch_wk, Kb,   MM);
    gemm_proj_mfma<0><<<dim3(32, 4),  blk, 0, stream>>>(sp_mem, sp_wk, KFb,  MM);
    gemm_proj_mfma<1><<<dim3(32, 4),  blk, 0, stream>>>(ch_mem, ch_wv, Vtb,  MM);
    gemm_proj_mfma<1><<<dim3(32, 4),  blk, 0, stream>>>(sp_mem, sp_wv, VFtb, MM);
    row_stats_bf16<<<dim3(NBQ / 4), blk, 0, stream>>>(QFb, qm, qv);
    row_stats_bf16<<<dim3(MM / 4),  blk, 0, stream>>>(KFb, km, kv);
    fused_attn_mfma<<<dim3(NBQ / 32), blk, 0, stream>>>(
        Qb, QFb, Kb, KFb, Vtb, VFtb, qm, qv, km, kv, out);
}

// Round 5
// 358.960 us; speedup vs baseline: 1.2278x; 1.2278x over previous
//
#include <hip/hip_runtime.h>

#define NBQ 12544
#define DM  256
#define MM  2048

typedef __attribute__((ext_vector_type(8))) __bf16 bf16x8;
typedef __attribute__((ext_vector_type(4))) float  floatx4;

__device__ __forceinline__ ushort f2bf(float x) {
    unsigned u = __float_as_uint(x);
    u += 0x7fffu + ((u >> 16) & 1u);   // RNE
    return (ushort)(u >> 16);
}
__device__ __forceinline__ float bf2f(ushort h) {
    return __uint_as_float(((unsigned)h) << 16);
}

// ---------------- ALL projections in one launch: C = A(fp32) * W(fp32)^T, bf16 out ----
// Block routing: [0,784) x@ch_wq->Qb; [784,1568) x@sp_wq->QFb; [1568,1696) ch_mem@ch_wk->Kb;
// [1696,1824) sp_mem@sp_wk->KFb; [1824,1952) ch_mem@ch_wv->Vt (transposed);
// [1952,2080) sp_mem@sp_wv->VFt (transposed).
__global__ __launch_bounds__(256) void gemm_proj_all(
    const float* __restrict__ x,      const float* __restrict__ ch_mem,
    const float* __restrict__ ch_wq,  const float* __restrict__ ch_wk,
    const float* __restrict__ ch_wv,  const float* __restrict__ sp_mem,
    const float* __restrict__ sp_wq,  const float* __restrict__ sp_wk,
    const float* __restrict__ sp_wv,
    ushort* __restrict__ Qb,  ushort* __restrict__ QFb,
    ushort* __restrict__ Kb,  ushort* __restrict__ KFb,
    ushort* __restrict__ Vtb, ushort* __restrict__ VFtb)
{
    __shared__ ushort As[64][72];   // [row][k], 144B stride -> uniform 2-way
    __shared__ ushort Ws[64][72];

    int bid = blockIdx.x;
    const float* A; const float* W; ushort* C; int nrows, trans;
    if (bid < 1568) {
        if (bid < 784) { A = x; W = ch_wq; C = Qb; }
        else           { A = x; W = sp_wq; C = QFb; bid -= 784; }
        nrows = NBQ; trans = 0;
    } else if (bid < 1824) {
        if (bid < 1696) { A = ch_mem; W = ch_wk; C = Kb;  bid -= 1568; }
        else            { A = sp_mem; W = sp_wk; C = KFb; bid -= 1696; }
        nrows = MM; trans = 0;
    } else {
        if (bid < 1952) { A = ch_mem; W = ch_wv; C = Vtb;  bid -= 1824; }
        else            { A = sp_mem; W = sp_wv; C = VFtb; bid -= 1952; }
        nrows = MM; trans = 1;
    }
    const int r0 = (bid >> 2) * 64;
    const int c0 = (bid & 3) * 64;

    const int tid  = threadIdx.x;
    const int wv   = tid >> 6;
    const int lane = tid & 63;
    const int quad = lane >> 4;
    const int l16  = lane & 15;
    const int rw = (wv & 1) * 32;
    const int cw = (wv >> 1) * 32;

    floatx4 acc[2][2];
    #pragma unroll
    for (int i = 0; i < 2; ++i)
        #pragma unroll
        for (int j = 0; j < 2; ++j)
            acc[i][j] = (floatx4){0.f, 0.f, 0.f, 0.f};

    for (int d0 = 0; d0 < 256; d0 += 64) {
        __syncthreads();
        #pragma unroll
        for (int it = 0; it < 4; ++it) {
            int idx = tid + it * 256;          // 1024 float4-chunks: 64 rows x 16
            int r = idx >> 4, c4 = (idx & 15) * 4;
            float4 a4 = *(const float4*)(A + (size_t)(r0 + r) * 256 + d0 + c4);
            float4 w4 = *(const float4*)(W + (size_t)(c0 + r) * 256 + d0 + c4);
            ushort4 ab, wb;
            ab.x = f2bf(a4.x); ab.y = f2bf(a4.y); ab.z = f2bf(a4.z); ab.w = f2bf(a4.w);
            wb.x = f2bf(w4.x); wb.y = f2bf(w4.y); wb.z = f2bf(w4.z); wb.w = f2bf(w4.w);
            *(ushort4*)&As[r][c4] = ab;
            *(ushort4*)&Ws[r][c4] = wb;
        }
        __syncthreads();
        #pragma unroll
        for (int kk = 0; kk < 64; kk += 32) {
            bf16x8 aA0 = *(const bf16x8*)&As[rw + l16][kk + quad * 8];
            bf16x8 aA1 = *(const bf16x8*)&As[rw + 16 + l16][kk + quad * 8];
            bf16x8 bW0 = *(const bf16x8*)&Ws[cw + l16][kk + quad * 8];
            bf16x8 bW1 = *(const bf16x8*)&Ws[cw + 16 + l16][kk + quad * 8];
            acc[0][0] = __builtin_amdgcn_mfma_f32_16x16x32_bf16(aA0, bW0, acc[0][0], 0, 0, 0);
            acc[0][1] = __builtin_amdgcn_mfma_f32_16x16x32_bf16(aA0, bW1, acc[0][1], 0, 0, 0);
            acc[1][0] = __builtin_amdgcn_mfma_f32_16x16x32_bf16(aA1, bW0, acc[1][0], 0, 0, 0);
            acc[1][1] = __builtin_amdgcn_mfma_f32_16x16x32_bf16(aA1, bW1, acc[1][1], 0, 0, 0);
        }
    }

    if (!trans) {
        #pragma unroll
        for (int ag = 0; ag < 2; ++ag)
            #pragma unroll
            for (int cg = 0; cg < 2; ++cg)
                #pragma unroll
                for (int i = 0; i < 4; ++i)
                    C[(size_t)(r0 + rw + ag * 16 + quad * 4 + i) * 256
                      + c0 + cw + cg * 16 + l16] = f2bf(acc[ag][cg][i]);
    } else {
        __syncthreads();  // done with Ws tiles
        #pragma unroll
        for (int ag = 0; ag < 2; ++ag)
            #pragma unroll
            for (int cg = 0; cg < 2; ++cg)
                #pragma unroll
                for (int i = 0; i < 4; ++i)
                    Ws[cw + cg * 16 + l16][rw + ag * 16 + quad * 4 + i] = f2bf(acc[ag][cg][i]);
        __syncthreads();
        const int col = tid >> 2;
        const int seg = (tid & 3) * 16;
        #pragma unroll
        for (int j = 0; j < 2; ++j)
            *(uint4*)(C + (size_t)(c0 + col) * nrows + r0 + seg + j * 8) =
                *(const uint4*)&Ws[col][seg + j * 8];
    }
}

// ---------------- row stats (QF rows then KF rows), one launch ----------------
__global__ __launch_bounds__(256) void row_stats_all(
    const ushort* __restrict__ QFb, const ushort* __restrict__ KFb,
    float* __restrict__ qm, float* __restrict__ qv,
    float* __restrict__ km, float* __restrict__ kv)
{
    const int rt   = blockIdx.x * 4 + (threadIdx.x >> 6);
    const int lane = threadIdx.x & 63;
    const ushort* X; float* mean; float* var; int row;
    if (rt < NBQ) { X = QFb; mean = qm; var = qv; row = rt; }
    else          { X = KFb; mean = km; var = kv; row = rt - NBQ; }
    ushort4 u = *(const ushort4*)(X + (size_t)row * 256 + lane * 4);
    float a = bf2f(u.x), b = bf2f(u.y), c = bf2f(u.z), d = bf2f(u.w);
    float s  = a + b + c + d;
    float ss = a * a + b * b + c * c + d * d;
    #pragma unroll
    for (int off = 32; off > 0; off >>= 1) {
        s  += __shfl_down(s, off);
        ss += __shfl_down(ss, off);
    }
    if (lane == 0) {
        float m = s * (1.f / 256.f);
        mean[row] = m;
        var[row]  = (ss - 256.f * m * m) * (1.f / 255.f);
    }
}

// ---------------- fused dual attention, MFMA, 32-key tiles (round-2 structure) ------
// Block: 32 queries, 4 waves. Wave w: qsel=w&1, ksel=w>>1 (score k-half == PV d-half).
// V/VF staged in LDS with chunk-major XOR-swizzled layout (uniform-2 banks both ways).
__global__ __launch_bounds__(256, 2) void fused_attn_mfma(
    const ushort* __restrict__ Qb,  const ushort* __restrict__ QFb,
    const ushort* __restrict__ Kb,  const ushort* __restrict__ KFb,
    const ushort* __restrict__ Vtb, const ushort* __restrict__ VFtb,
    const float* __restrict__ qm_, const float* __restrict__ qv_,
    const float* __restrict__ km_, const float* __restrict__ kv_,
    float* __restrict__ out)
{
    __shared__ ushort K_lds[32][264];     // 528B stride -> uniform 2-way
    __shared__ ushort KF_lds[32][264];
    __shared__ ushort Vt_lds[4][256][8];  // [kchunk][d ^ (kc<<2)][k&7] -> uniform 2-way
    __shared__ ushort VFt_lds[4][256][8];
    __shared__ ushort P_lds[2][32][40];   // [branch][q][key], 80B stride -> uniform 2-way
    // total LDS = 2*16896 + 2*16384 + 5120 = 71680 B -> 2 blocks/CU

    const int tid  = threadIdx.x;
    const int wv   = tid >> 6;
    const int lane = tid & 63;
    const int quad = lane >> 4;
    const int l16  = lane & 15;
    const int qsel = wv & 1;
    const int ksel = wv >> 1;
    const int q0   = blockIdx.x * 32;

    // Q A-fragments in registers for the whole key loop
    bf16x8 aQ[8], aQF[8];
    {
        const ushort* qp  = Qb  + (size_t)(q0 + qsel * 16 + l16) * DM + quad * 8;
        const ushort* qfp = QFb + (size_t)(q0 + qsel * 16 + l16) * DM + quad * 8;
        #pragma unroll
        for (int s = 0; s < 8; ++s) {
            aQ[s]  = *(const bf16x8*)(qp  + s * 32);
            aQF[s] = *(const bf16x8*)(qfp + s * 32);
        }
    }
    float qmv[4], qvv[4];
    #pragma unroll
    for (int r = 0; r < 4; ++r) {
        int qg = q0 + qsel * 16 + quad * 4 + r;
        qmv[r] = qm_[qg]; qvv[r] = qv_[qg];
    }

    floatx4 acc_c[8], acc_s[8];
    #pragma unroll
    for (int t = 0; t < 8; ++t) {
        acc_c[t] = (floatx4){0.f, 0.f, 0.f, 0.f};
        acc_s[t] = (floatx4){0.f, 0.f, 0.f, 0.f};
    }
    float denc_r[4] = {0.f, 0.f, 0.f, 0.f};
    float dens_r[4] = {0.f, 0.f, 0.f, 0.f};

    for (int kt = 0; kt < MM; kt += 32) {
        __syncthreads();  // previous tile's LDS fully consumed
        // stage K/KF (32 x 256): 1024 uint4-chunks = 32 rows x 32 chunks
        #pragma unroll
        for (int it = 0; it < 4; ++it) {
            int idx = tid + it * 256;
            int r = idx >> 5, c8 = (idx & 31) * 8;
            *(uint4*)&K_lds[r][c8]  = *(const uint4*)(Kb  + (size_t)(kt + r) * DM + c8);
            *(uint4*)&KF_lds[r][c8] = *(const uint4*)(KFb + (size_t)(kt + r) * DM + c8);
        }
        // stage Vt/VFt (256 dims x 32 keys), chunk-major + XOR swizzle
        #pragma unroll
        for (int it = 0; it < 4; ++it) {
            int idx = tid + it * 256;
            int d = idx >> 2, kc = idx & 3;
            int dsw = d ^ (kc << 2);
            *(uint4*)&Vt_lds[kc][dsw][0]  = *(const uint4*)(Vtb  + (size_t)d * MM + kt + kc * 8);
            *(uint4*)&VFt_lds[kc][dsw][0] = *(const uint4*)(VFtb + (size_t)d * MM + kt + kc * 8);
        }
        __syncthreads();

        // ---- scores: 16q x 16k per wave, both branches ----
        floatx4 sc = (floatx4){0.f, 0.f, 0.f, 0.f};
        floatx4 sd = (floatx4){0.f, 0.f, 0.f, 0.f};
        #pragma unroll
        for (int s = 0; s < 8; ++s) {
            bf16x8 bK  = *(const bf16x8*)&K_lds[ksel * 16 + l16][s * 32 + quad * 8];
            bf16x8 bKF = *(const bf16x8*)&KF_lds[ksel * 16 + l16][s * 32 + quad * 8];
            sc = __builtin_amdgcn_mfma_f32_16x16x32_bf16(aQ[s],  bK,  sc, 0, 0, 0);
            sd = __builtin_amdgcn_mfma_f32_16x16x32_bf16(aQF[s], bKF, sd, 0, 0, 0);
        }
        // ---- epilogue: exp(score/16), SSIM -> P (bf16), denominator partials ----
        {
            float kmv = km_[kt + ksel * 16 + l16];
            float kvv = kv_[kt + ksel * 16 + l16];
            #pragma unroll
            for (int r = 0; r < 4; ++r) {
                float p1  = __expf(sc[r] * 0.0625f);
                float mp  = qmv[r] * kmv;
                float cov = (sd[r] - 256.f * mp) * (1.f / 255.f);
                float num = (2.f * mp + 0.01f) * (2.f * cov + 0.03f);
                float den = (qmv[r] * qmv[r] + kmv * kmv + 0.01f) * (qvv[r] + kvv + 0.03f);
                float p2  = __expf(num / (den + 1e-8f));
                P_lds[0][qsel * 16 + quad * 4 + r][ksel * 16 + l16] = f2bf(p1);
                P_lds[1][qsel * 16 + quad * 4 + r][ksel * 16 + l16] = f2bf(p2);
                denc_r[r] += p1;
                dens_r[r] += p2;
            }
        }
        __syncthreads();
        // ---- PV: A = P rows (own q-half), B = Vt swizzled LDS (own d-half), K=32 ----
        bf16x8 aPc = *(const bf16x8*)&P_lds[0][qsel * 16 + l16][quad * 8];
        bf16x8 aPs = *(const bf16x8*)&P_lds[1][qsel * 16 + l16][quad * 8];
        #pragma unroll
        for (int t = 0; t < 8; ++t) {
            int drow = (ksel * 128 + t * 16 + l16) ^ (quad << 2);
            bf16x8 bV  = *(const bf16x8*)&Vt_lds[quad][drow][0];
            bf16x8 bVF = *(const bf16x8*)&VFt_lds[quad][drow][0];
            acc_c[t] = __builtin_amdgcn_mfma_f32_16x16x32_bf16(aPc, bV,  acc_c[t], 0, 0, 0);
            acc_s[t] = __builtin_amdgcn_mfma_f32_16x16x32_bf16(aPs, bVF, acc_s[t], 0, 0, 0);
        }
    }

    // ---- denominators: reduce over 16 key-lanes, combine k-halves via LDS ----
    #pragma unroll
    for (int r = 0; r < 4; ++r) {
        #pragma unroll
        for (int m = 1; m < 16; m <<= 1) {
            denc_r[r] += __shfl_xor(denc_r[r], m, 64);
            dens_r[r] += __shfl_xor(dens_r[r], m, 64);
        }
    }
    __syncthreads();  // all PV reads of P done; safe to alias
    float* denbuf = (float*)P_lds;  // [2 branch][2 ksel][32 q]
    if (l16 == 0) {
        #pragma unroll
        for (int r = 0; r < 4; ++r) {
            int q32 = qsel * 16 + quad * 4 + r;
            denbuf[ksel * 32 + q32]      = denc_r[r];
            denbuf[64 + ksel * 32 + q32] = dens_r[r];
        }
    }
    __syncthreads();
    #pragma unroll
    for (int r = 0; r < 4; ++r) {
        int q32 = qsel * 16 + quad * 4 + r;
        float rc = 1.f / (denbuf[q32] + denbuf[32 + q32]);
        float rs = 1.f / (denbuf[64 + q32] + denbuf[96 + q32]);
        float* orow = out + (size_t)(q0 + q32) * DM + ksel * 128 + l16;
        #pragma unroll
        for (int t = 0; t < 8; ++t)
            orow[t * 16] = acc_c[t][r] * rc + acc_s[t][r] * rs;
    }
}

extern "C" void kernel_launch(void* const* d_in, const int* in_sizes, int n_in,
                              void* d_out, int out_size, void* d_ws, size_t ws_size,
                              hipStream_t stream)
{
    const float* x      = (const float*)d_in[0];
    const float* ch_mem = (const float*)d_in[1];
    const float* ch_wq  = (const float*)d_in[2];
    const float* ch_wk  = (const float*)d_in[3];
    const float* ch_wv  = (const float*)d_in[4];
    const float* sp_mem = (const float*)d_in[5];
    const float* sp_wq  = (const float*)d_in[6];
    const float* sp_wk  = (const float*)d_in[7];
    const float* sp_wv  = (const float*)d_in[8];
    float* out = (float*)d_out;

    ushort* Qb   = (ushort*)d_ws;                 // [12544][256]
    ushort* QFb  = Qb   + (size_t)NBQ * DM;
    ushort* Kb   = QFb  + (size_t)NBQ * DM;       // [2048][256]
    ushort* KFb  = Kb   + (size_t)MM * DM;
    ushort* Vtb  = KFb  + (size_t)MM * DM;        // [256][2048] transposed
    ushort* VFtb = Vtb  + (size_t)MM * DM;
    float*  qm   = (float*)(VFtb + (size_t)MM * DM);
    float*  qv   = qm + NBQ;
    float*  km   = qv + NBQ;
    float*  kv   = km + MM;

    dim3 blk(256);
    gemm_proj_all<<<dim3(2080), blk, 0, stream>>>(
        x, ch_mem, ch_wq, ch_wk, ch_wv, sp_mem, sp_wq, sp_wk, sp_wv,
        Qb, QFb, Kb, KFb, Vtb, VFtb);
    row_stats_all<<<dim3((NBQ + MM) / 4), blk, 0, stream>>>(QFb, KFb, qm, qv, km, kv);
    fused_attn_mfma<<<dim3(NBQ / 32), blk, 0, stream>>>(
        Qb, QFb, Kb, KFb, Vtb, VFtb, qm, qv, km, kv, out);
}

// Round 6
// 348.918 us; speedup vs baseline: 1.2631x; 1.0288x over previous
//
#include <hip/hip_runtime.h>

#define NBQ 12544
#define DM  256
#define MM  2048

typedef __attribute__((ext_vector_type(8)))  __bf16 bf16x8;
typedef __attribute__((ext_vector_type(4)))  float  floatx4;
typedef __attribute__((ext_vector_type(16))) float  floatx16;

__device__ __forceinline__ ushort f2bf(float x) {
    unsigned u = __float_as_uint(x);
    u += 0x7fffu + ((u >> 16) & 1u);   // RNE
    return (ushort)(u >> 16);
}
__device__ __forceinline__ float bf2f(ushort h) {
    return __uint_as_float(((unsigned)h) << 16);
}

// ---------------- ALL projections in one launch: C = A(fp32) * W(fp32)^T, bf16 out ----
__global__ __launch_bounds__(256) void gemm_proj_all(
    const float* __restrict__ x,      const float* __restrict__ ch_mem,
    const float* __restrict__ ch_wq,  const float* __restrict__ ch_wk,
    const float* __restrict__ ch_wv,  const float* __restrict__ sp_mem,
    const float* __restrict__ sp_wq,  const float* __restrict__ sp_wk,
    const float* __restrict__ sp_wv,
    ushort* __restrict__ Qb,  ushort* __restrict__ QFb,
    ushort* __restrict__ Kb,  ushort* __restrict__ KFb,
    ushort* __restrict__ Vtb, ushort* __restrict__ VFtb)
{
    __shared__ ushort As[64][72];
    __shared__ ushort Ws[64][72];

    int bid = blockIdx.x;
    const float* A; const float* W; ushort* C; int nrows, trans;
    if (bid < 1568) {
        if (bid < 784) { A = x; W = ch_wq; C = Qb; }
        else           { A = x; W = sp_wq; C = QFb; bid -= 784; }
        nrows = NBQ; trans = 0;
    } else if (bid < 1824) {
        if (bid < 1696) { A = ch_mem; W = ch_wk; C = Kb;  bid -= 1568; }
        else            { A = sp_mem; W = sp_wk; C = KFb; bid -= 1696; }
        nrows = MM; trans = 0;
    } else {
        if (bid < 1952) { A = ch_mem; W = ch_wv; C = Vtb;  bid -= 1824; }
        else            { A = sp_mem; W = sp_wv; C = VFtb; bid -= 1952; }
        nrows = MM; trans = 1;
    }
    const int r0 = (bid >> 2) * 64;
    const int c0 = (bid & 3) * 64;

    const int tid  = threadIdx.x;
    const int wv   = tid >> 6;
    const int lane = tid & 63;
    const int quad = lane >> 4;
    const int l16  = lane & 15;
    const int rw = (wv & 1) * 32;
    const int cw = (wv >> 1) * 32;

    floatx4 acc[2][2];
    #pragma unroll
    for (int i = 0; i < 2; ++i)
        #pragma unroll
        for (int j = 0; j < 2; ++j)
            acc[i][j] = (floatx4){0.f, 0.f, 0.f, 0.f};

    for (int d0 = 0; d0 < 256; d0 += 64) {
        __syncthreads();
        #pragma unroll
        for (int it = 0; it < 4; ++it) {
            int idx = tid + it * 256;
            int r = idx >> 4, c4 = (idx & 15) * 4;
            float4 a4 = *(const float4*)(A + (size_t)(r0 + r) * 256 + d0 + c4);
            float4 w4 = *(const float4*)(W + (size_t)(c0 + r) * 256 + d0 + c4);
            ushort4 ab, wb;
            ab.x = f2bf(a4.x); ab.y = f2bf(a4.y); ab.z = f2bf(a4.z); ab.w = f2bf(a4.w);
            wb.x = f2bf(w4.x); wb.y = f2bf(w4.y); wb.z = f2bf(w4.z); wb.w = f2bf(w4.w);
            *(ushort4*)&As[r][c4] = ab;
            *(ushort4*)&Ws[r][c4] = wb;
        }
        __syncthreads();
        #pragma unroll
        for (int kk = 0; kk < 64; kk += 32) {
            bf16x8 aA0 = *(const bf16x8*)&As[rw + l16][kk + quad * 8];
            bf16x8 aA1 = *(const bf16x8*)&As[rw + 16 + l16][kk + quad * 8];
            bf16x8 bW0 = *(const bf16x8*)&Ws[cw + l16][kk + quad * 8];
            bf16x8 bW1 = *(const bf16x8*)&Ws[cw + 16 + l16][kk + quad * 8];
            acc[0][0] = __builtin_amdgcn_mfma_f32_16x16x32_bf16(aA0, bW0, acc[0][0], 0, 0, 0);
            acc[0][1] = __builtin_amdgcn_mfma_f32_16x16x32_bf16(aA0, bW1, acc[0][1], 0, 0, 0);
            acc[1][0] = __builtin_amdgcn_mfma_f32_16x16x32_bf16(aA1, bW0, acc[1][0], 0, 0, 0);
            acc[1][1] = __builtin_amdgcn_mfma_f32_16x16x32_bf16(aA1, bW1, acc[1][1], 0, 0, 0);
        }
    }

    if (!trans) {
        #pragma unroll
        for (int ag = 0; ag < 2; ++ag)
            #pragma unroll
            for (int cg = 0; cg < 2; ++cg)
                #pragma unroll
                for (int i = 0; i < 4; ++i)
                    C[(size_t)(r0 + rw + ag * 16 + quad * 4 + i) * 256
                      + c0 + cw + cg * 16 + l16] = f2bf(acc[ag][cg][i]);
    } else {
        __syncthreads();
        #pragma unroll
        for (int ag = 0; ag < 2; ++ag)
            #pragma unroll
            for (int cg = 0; cg < 2; ++cg)
                #pragma unroll
                for (int i = 0; i < 4; ++i)
                    Ws[cw + cg * 16 + l16][rw + ag * 16 + quad * 4 + i] = f2bf(acc[ag][cg][i]);
        __syncthreads();
        const int col = tid >> 2;
        const int seg = (tid & 3) * 16;
        #pragma unroll
        for (int j = 0; j < 2; ++j)
            *(uint4*)(C + (size_t)(c0 + col) * nrows + r0 + seg + j * 8) =
                *(const uint4*)&Ws[col][seg + j * 8];
    }
}

// ---------------- row stats (QF rows then KF rows), one launch ----------------
__global__ __launch_bounds__(256) void row_stats_all(
    const ushort* __restrict__ QFb, const ushort* __restrict__ KFb,
    float* __restrict__ qm, float* __restrict__ qv,
    float* __restrict__ km, float* __restrict__ kv)
{
    const int rt   = blockIdx.x * 4 + (threadIdx.x >> 6);
    const int lane = threadIdx.x & 63;
    const ushort* X; float* mean; float* var; int row;
    if (rt < NBQ) { X = QFb; mean = qm; var = qv; row = rt; }
    else          { X = KFb; mean = km; var = kv; row = rt - NBQ; }
    ushort4 u = *(const ushort4*)(X + (size_t)row * 256 + lane * 4);
    float a = bf2f(u.x), b = bf2f(u.y), c = bf2f(u.z), d = bf2f(u.w);
    float s  = a + b + c + d;
    float ss = a * a + b * b + c * c + d * d;
    #pragma unroll
    for (int off = 32; off > 0; off >>= 1) {
        s  += __shfl_down(s, off);
        ss += __shfl_down(ss, off);
    }
    if (lane == 0) {
        float m = s * (1.f / 256.f);
        mean[row] = m;
        var[row]  = (ss - 256.f * m * m) * (1.f / 255.f);
    }
}

// ---------------- fused attention: one branch per block, 64q, 64-key tiles, 32x32 MFMA
// grid 392: bid<196 -> channel branch, else spatial (SSIM). Output combined via
// atomicAdd into zeroed out (exactly 2 adds/element -> deterministic).
// Score waves: (qs=w&1, ks=w>>1) -> 32q x 32k tile, K=256 (Q A-frags in regs).
// PV waves: d-quarter wv*64, all 64 q. C-layout: col=lane&31, row=(r&3)+8*(r>>2)+4*(lane>>5).
__global__ __launch_bounds__(256, 2) void fused_attn_big(
    const ushort* __restrict__ Qb,  const ushort* __restrict__ QFb,
    const ushort* __restrict__ Kb,  const ushort* __restrict__ KFb,
    const ushort* __restrict__ Vtb, const ushort* __restrict__ VFtb,
    const float* __restrict__ qm_, const float* __restrict__ qv_,
    const float* __restrict__ km_, const float* __restrict__ kv_,
    float* __restrict__ out)
{
    __shared__ ushort K_lds[64][264];   // 528B stride (16B-aligned), uniform banks
    __shared__ ushort Vt_lds[256][72];  // [d][key], 144B stride, uniform banks
    __shared__ ushort P_lds[64][72];    // [q][key]
    __shared__ float  denbuf[2][64];    // [ks][q]
    // total LDS = 33792 + 36864 + 9216 + 512 = 80384 B -> 2 blocks/CU

    const int tid  = threadIdx.x;
    const int wv   = tid >> 6;
    const int lane = tid & 63;
    const int l32  = lane & 31;
    const int half = lane >> 5;

    const bool spatial = (blockIdx.x >= 196);
    const int q0 = (spatial ? (int)blockIdx.x - 196 : (int)blockIdx.x) * 64;
    const ushort* Qp = spatial ? QFb  : Qb;
    const ushort* Kp = spatial ? KFb  : Kb;
    const ushort* Vp = spatial ? VFtb : Vtb;

    const int qs = wv & 1;    // score-role: q half
    const int ks = wv >> 1;   // score-role: key half of the 64-tile

    // Q A-fragments in registers for the whole key loop (one branch): A[m=l32][k]
    bf16x8 aQ[16];
    {
        const ushort* qp = Qp + (size_t)(q0 + qs * 32 + l32) * DM + half * 8;
        #pragma unroll
        for (int s = 0; s < 16; ++s) aQ[s] = *(const bf16x8*)(qp + s * 16);
    }
    // SSIM per-row stats for this lane's C-layout rows
    float qmr[16], qvr[16];
    if (spatial) {
        #pragma unroll
        for (int reg = 0; reg < 16; ++reg) {
            int row = q0 + qs * 32 + (reg & 3) + 8 * (reg >> 2) + 4 * half;
            qmr[reg] = qm_[row]; qvr[reg] = qv_[row];
        }
    }

    floatx16 accO[2][2];   // [q-tile][d-subtile], d-quarter = wv*64
    #pragma unroll
    for (int a = 0; a < 2; ++a)
        #pragma unroll
        for (int b = 0; b < 2; ++b)
            #pragma unroll
            for (int i = 0; i < 16; ++i) accO[a][b][i] = 0.f;
    float den_r[16];
    #pragma unroll
    for (int i = 0; i < 16; ++i) den_r[i] = 0.f;

    for (int kt = 0; kt < MM; kt += 64) {
        __syncthreads();  // prev tile's K/Vt/P fully consumed
        // stage K (64 x 256): 2048 uint4 = 64 rows x 32 chunks
        #pragma unroll
        for (int it = 0; it < 8; ++it) {
            int idx = tid + it * 256;
            int r = idx >> 5, c8 = (idx & 31) * 8;
            *(uint4*)&K_lds[r][c8] = *(const uint4*)(Kp + (size_t)(kt + r) * DM + c8);
        }
        // stage Vt (256 d x 64 keys): 2048 uint4 = 256 rows x 8 chunks
        #pragma unroll
        for (int it = 0; it < 8; ++it) {
            int idx = tid + it * 256;
            int d = idx >> 3, k8 = (idx & 7) * 8;
            *(uint4*)&Vt_lds[d][k8] = *(const uint4*)(Vp + (size_t)d * MM + kt + k8);
        }
        __syncthreads();

        // ---- scores: 32q x 32k per wave, K=256 ----
        floatx16 S;
        #pragma unroll
        for (int i = 0; i < 16; ++i) S[i] = 0.f;
        #pragma unroll
        for (int s = 0; s < 16; ++s) {
            bf16x8 bK = *(const bf16x8*)&K_lds[ks * 32 + l32][s * 16 + half * 8];
            S = __builtin_amdgcn_mfma_f32_32x32x16_bf16(aQ[s], bK, S, 0, 0, 0);
        }

        // ---- epilogue -> P (bf16) + den partials ----
        {
            int kcol = kt + ks * 32 + l32;
            float kmv = 0.f, kvv = 0.f;
            if (spatial) { kmv = km_[kcol]; kvv = kv_[kcol]; }
            #pragma unroll
            for (int reg = 0; reg < 16; ++reg) {
                float p;
                if (!spatial) {
                    p = __expf(S[reg] * 0.0625f);
                } else {
                    float mp  = qmr[reg] * kmv;
                    float cov = (S[reg] - 256.f * mp) * (1.f / 255.f);
                    float num = (2.f * mp + 0.01f) * (2.f * cov + 0.03f);
                    float den = (qmr[reg] * qmr[reg] + kmv * kmv + 0.01f) * (qvr[reg] + kvv + 0.03f);
                    p = __expf(num / (den + 1e-8f));
                }
                int rloc = qs * 32 + (reg & 3) + 8 * (reg >> 2) + 4 * half;
                P_lds[rloc][ks * 32 + l32] = f2bf(p);
                den_r[reg] += p;
            }
        }
        __syncthreads();

        // ---- PV: wave = d-quarter (wv*64), A=P rows, B=Vt rows, 4 k-chunks ----
        #pragma unroll
        for (int kc = 0; kc < 4; ++kc) {
            bf16x8 aP0 = *(const bf16x8*)&P_lds[l32][kc * 16 + half * 8];
            bf16x8 aP1 = *(const bf16x8*)&P_lds[32 + l32][kc * 16 + half * 8];
            bf16x8 bV0 = *(const bf16x8*)&Vt_lds[wv * 64 + l32][kc * 16 + half * 8];
            bf16x8 bV1 = *(const bf16x8*)&Vt_lds[wv * 64 + 32 + l32][kc * 16 + half * 8];
            accO[0][0] = __builtin_amdgcn_mfma_f32_32x32x16_bf16(aP0, bV0, accO[0][0], 0, 0, 0);
            accO[0][1] = __builtin_amdgcn_mfma_f32_32x32x16_bf16(aP0, bV1, accO[0][1], 0, 0, 0);
            accO[1][0] = __builtin_amdgcn_mfma_f32_32x32x16_bf16(aP1, bV0, accO[1][0], 0, 0, 0);
            accO[1][1] = __builtin_amdgcn_mfma_f32_32x32x16_bf16(aP1, bV1, accO[1][1], 0, 0, 0);
        }
    }

    // ---- denominators: reduce over 32 key-cols, publish per ks-half ----
    #pragma unroll
    for (int reg = 0; reg < 16; ++reg)
        #pragma unroll
        for (int m = 1; m < 32; m <<= 1)
            den_r[reg] += __shfl_xor(den_r[reg], m, 64);
    if (l32 == 0) {
        #pragma unroll
        for (int reg = 0; reg < 16; ++reg) {
            int rloc = qs * 32 + (reg & 3) + 8 * (reg >> 2) + 4 * half;
            denbuf[ks][rloc] = den_r[reg];
        }
    }
    __syncthreads();

    // ---- output: normalize + atomicAdd combine (2 adds/element, deterministic) ----
    #pragma unroll
    for (int qt = 0; qt < 2; ++qt) {
        #pragma unroll
        for (int reg = 0; reg < 16; ++reg) {
            int rloc = qt * 32 + (reg & 3) + 8 * (reg >> 2) + 4 * half;
            float rden = 1.f / (denbuf[0][rloc] + denbuf[1][rloc]);
            float* orow = out + (size_t)(q0 + rloc) * DM + wv * 64 + l32;
            atomicAdd(orow,      accO[qt][0][reg] * rden);
            atomicAdd(orow + 32, accO[qt][1][reg] * rden);
        }
    }
}

extern "C" void kernel_launch(void* const* d_in, const int* in_sizes, int n_in,
                              void* d_out, int out_size, void* d_ws, size_t ws_size,
                              hipStream_t stream)
{
    const float* x      = (const float*)d_in[0];
    const float* ch_mem = (const float*)d_in[1];
    const float* ch_wq  = (const float*)d_in[2];
    const float* ch_wk  = (const float*)d_in[3];
    const float* ch_wv  = (const float*)d_in[4];
    const float* sp_mem = (const float*)d_in[5];
    const float* sp_wq  = (const float*)d_in[6];
    const float* sp_wk  = (const float*)d_in[7];
    const float* sp_wv  = (const float*)d_in[8];
    float* out = (float*)d_out;

    ushort* Qb   = (ushort*)d_ws;                 // [12544][256]
    ushort* QFb  = Qb   + (size_t)NBQ * DM;
    ushort* Kb   = QFb  + (size_t)NBQ * DM;       // [2048][256]
    ushort* KFb  = Kb   + (size_t)MM * DM;
    ushort* Vtb  = KFb  + (size_t)MM * DM;        // [256][2048] transposed
    ushort* VFtb = Vtb  + (size_t)MM * DM;
    float*  qm   = (float*)(VFtb + (size_t)MM * DM);
    float*  qv   = qm + NBQ;
    float*  km   = qv + NBQ;
    float*  kv   = km + MM;

    hipMemsetAsync(d_out, 0, (size_t)out_size * sizeof(float), stream);

    dim3 blk(256);
    gemm_proj_all<<<dim3(2080), blk, 0, stream>>>(
        x, ch_mem, ch_wq, ch_wk, ch_wv, sp_mem, sp_wq, sp_wk, sp_wv,
        Qb, QFb, Kb, KFb, Vtb, VFtb);
    row_stats_all<<<dim3((NBQ + MM) / 4), blk, 0, stream>>>(QFb, KFb, qm, qv, km, kv);
    fused_attn_big<<<dim3(392), blk, 0, stream>>>(
        Qb, QFb, Kb, KFb, Vtb, VFtb, qm, qv, km, kv, out);
}